// Round 1
// baseline (1153.689 us; speedup 1.0000x reference)
//
#include <hip/hip_runtime.h>
#include <hip/hip_bf16.h>

typedef unsigned short u16;
typedef __bf16  bf16x8 __attribute__((ext_vector_type(8)));
typedef float   f32x4  __attribute__((ext_vector_type(4)));
typedef u16     u16x4  __attribute__((ext_vector_type(4)));

#define MFMA16(a, b, c) __builtin_amdgcn_mfma_f32_16x16x32_bf16((a), (b), (c), 0, 0, 0)

__device__ __forceinline__ u16 f2bf(float f) {
  union { float f; unsigned u; } v; v.f = f;
  unsigned r = v.u + 0x7fffu + ((v.u >> 16) & 1u);
  return (u16)(r >> 16);
}

// ---------- fp32 -> bf16 conversion (vectorized x4) ----------
__global__ void k_cvt(const float* __restrict__ src, u16* __restrict__ dst, int n4) {
  int i = blockIdx.x * blockDim.x + threadIdx.x;
  const int stride = gridDim.x * blockDim.x;
  for (; i < n4; i += stride) {
    f32x4 v = ((const f32x4*)src)[i];
    u16x4 o; o[0] = f2bf(v[0]); o[1] = f2bf(v[1]); o[2] = f2bf(v[2]); o[3] = f2bf(v[3]);
    ((u16x4*)dst)[i] = o;
  }
}

// ---------- copy past_k/past_v [B,H,3072,128] into cache [B,H,4096,128] rows 0..3071 ----------
__global__ void k_past(const float* __restrict__ src, float* __restrict__ dst, int n4) {
  int i = blockIdx.x * blockDim.x + threadIdx.x;
  const int stride = gridDim.x * blockDim.x;
  for (; i < n4; i += stride) {
    int bh  = i / 98304;           // TP*D/4
    int rem = i - bh * 98304;
    ((f32x4*)dst)[(size_t)bh * 131072 + rem] = ((const f32x4*)src)[i];  // S*D/4 = 131072
  }
}

// ---------- bf16 GEMM:  C[M=4096, N=2048] = A[M,K=2048] @ W[N,K]^T + bias ----------
// MODE 0: Q -> bf16 ws, scaled by 1/sqrt(128)
// MODE 1: K/V -> fp32 cache [B=4,H=16,4096,128] at time offset 3072
// MODE 2: O -> fp32 row-major [M,N]
template<int MODE>
__global__ __launch_bounds__(256)
void k_gemm(const u16* __restrict__ A, const u16* __restrict__ W,
            const float* __restrict__ bias,
            float* __restrict__ outf, u16* __restrict__ outb)
{
  constexpr int K = 2048;
  __shared__ u16 As[128 * 32];
  __shared__ u16 Bs[128 * 32];
  const int tid = threadIdx.x;
  const int l = tid & 63, w = tid >> 6;
  const int hi = l >> 4, lo = l & 15;
  const int m0 = blockIdx.x * 128, n0 = blockIdx.y * 128;
  const int wm = (w >> 1) * 64, wn = (w & 1) * 64;

  f32x4 acc[4][4] = {};

  const int fbase = tid * 8;
  for (int k0 = 0; k0 < K; k0 += 32) {
    __syncthreads();
#pragma unroll
    for (int i = 0; i < 2; ++i) {
      const int f  = i * 2048 + fbase;
      const int wb = i * 2048 + w * 512;      // wave-uniform LDS element base
      const u16* ga = A + (size_t)(m0 + (f >> 5)) * K + k0 + (f & 31);
      const u16* gb = W + (size_t)(n0 + (f >> 5)) * K + k0 + (f & 31);
      __builtin_amdgcn_global_load_lds((const __attribute__((address_space(1))) void*)ga,
                                       (__attribute__((address_space(3))) void*)(As + wb), 16, 0, 0);
      __builtin_amdgcn_global_load_lds((const __attribute__((address_space(1))) void*)gb,
                                       (__attribute__((address_space(3))) void*)(Bs + wb), 16, 0, 0);
    }
    __syncthreads();
    bf16x8 af[4], bfr[4];
#pragma unroll
    for (int mf = 0; mf < 4; ++mf)
      af[mf] = *(const bf16x8*)&As[(wm + mf * 16 + lo) * 32 + hi * 8];
#pragma unroll
    for (int nf = 0; nf < 4; ++nf)
      bfr[nf] = *(const bf16x8*)&Bs[(wn + nf * 16 + lo) * 32 + hi * 8];
#pragma unroll
    for (int mf = 0; mf < 4; ++mf)
#pragma unroll
      for (int nf = 0; nf < 4; ++nf)
        acc[mf][nf] = MFMA16(bfr[nf], af[mf], acc[mf][nf]);   // swapped -> C^T layout
  }

  // epilogue: lane holds C[m = ..+lo][n = ..+hi*4 + r], r = 0..3 consecutive cols
#pragma unroll
  for (int mf = 0; mf < 4; ++mf) {
    const int m = m0 + wm + mf * 16 + lo;
#pragma unroll
    for (int nf = 0; nf < 4; ++nf) {
      const int n = n0 + wn + nf * 16 + hi * 4;
      const f32x4 bv = *(const f32x4*)&bias[n];
      f32x4 v = acc[mf][nf] + bv;
      if constexpr (MODE == 0) {
        v *= 0.08838834764831845f;          // 1/sqrt(128) folded into q
        u16x4 o; o[0] = f2bf(v[0]); o[1] = f2bf(v[1]); o[2] = f2bf(v[2]); o[3] = f2bf(v[3]);
        *(u16x4*)&outb[(size_t)m * 2048 + n] = o;
      } else if constexpr (MODE == 1) {
        const int b = m >> 10, t = m & 1023;
        const int h = n >> 7,  d = n & 127;
        *(f32x4*)&outf[((size_t)((b * 16 + h) * 4096 + 3072 + t)) * 128 + d] = v;
      } else {
        *(f32x4*)&outf[(size_t)m * 2048 + n] = v;
      }
    }
  }
}

// ---------- flash attention ----------
// grid 256: bid -> (bh = bid>>2, qb = bid&3). 512 threads = 8 waves, 32 q-rows/wave.
// KV chunk = 64 keys; K/V read fp32 from cache, converted to bf16 into swizzled LDS.
__global__ __launch_bounds__(512)
void k_attn(const u16* __restrict__ qws, const float* __restrict__ kcache,
            const float* __restrict__ vcache, u16* __restrict__ attnws)
{
  __shared__ u16 Klds[64 * 128];     // [key][d], d XOR-swizzled by key&7
  __shared__ u16 Vt[128 * 64];       // [d][key], key XOR-swizzled by (d>>3)&7
  __shared__ u16 Plds[8][32 * 72];   // per-wave P [32 q][64 key], stride 72

  const int tid = threadIdx.x;
  const int l = tid & 63, w = tid >> 6;
  const int hi = l >> 4, lo = l & 15;
  const int bid = blockIdx.x;
  const int qb = bid & 3, bh = bid >> 2;
  const int b = bh >> 4, h = bh & 15;

  // hoist Q fragments (already scaled): A-operand layout, 2 m-frags x 4 k-chunks
  bf16x8 qf[2][4];
#pragma unroll
  for (int mf = 0; mf < 2; ++mf) {
    const int qrow = b * 1024 + qb * 256 + w * 32 + mf * 16 + lo;
    const u16* qp = qws + (size_t)qrow * 2048 + h * 128;
#pragma unroll
    for (int kc = 0; kc < 4; ++kc)
      qf[mf][kc] = *(const bf16x8*)(qp + kc * 32 + hi * 8);
  }

  f32x4 acc_o[2][8] = {};
  float mrow[2][4], lrow[2][4];
#pragma unroll
  for (int mf = 0; mf < 2; ++mf)
#pragma unroll
    for (int r = 0; r < 4; ++r) { mrow[mf][r] = -1e30f; lrow[mf][r] = 0.f; }

  const float* kbase = kcache + (size_t)bh * 524288;   // 4096*128
  const float* vbase = vcache + (size_t)bh * 524288;
  u16* Pw = Plds[w];
  const int vd0 = (tid & 31) * 4, vk0 = (tid >> 5) * 4;

  for (int ci = 0; ci < 64; ++ci) {
    __syncthreads();
    // ---- stage K chunk [64][128] fp32 -> bf16, row-swizzled
    const float* kch = kbase + ci * 8192;
#pragma unroll
    for (int i = 0; i < 4; ++i) {
      const int e = (i * 512 + tid) * 4;
      f32x4 kv = *(const f32x4*)(kch + e);
      const int row = e >> 7, col = e & 127;
      u16x4 o; o[0] = f2bf(kv[0]); o[1] = f2bf(kv[1]); o[2] = f2bf(kv[2]); o[3] = f2bf(kv[3]);
      *(u16x4*)&Klds[row * 128 + (col ^ ((row & 7) << 3))] = o;
    }
    // ---- stage V chunk transposed: Vt[d][k], swizzled
    const float* vch = vbase + ci * 8192;
    {
      f32x4 vv[4];
#pragma unroll
      for (int i = 0; i < 4; ++i)
        vv[i] = *(const f32x4*)(vch + (vk0 + i) * 128 + vd0);
#pragma unroll
      for (int j = 0; j < 4; ++j) {
        const int d = vd0 + j;
        const int kx = vk0 ^ (((d >> 3) & 7) << 3);
        u16x4 o; o[0] = f2bf(vv[0][j]); o[1] = f2bf(vv[1][j]); o[2] = f2bf(vv[2][j]); o[3] = f2bf(vv[3][j]);
        *(u16x4*)&Vt[d * 64 + kx] = o;
      }
    }
    __syncthreads();

    // ---- S = Q @ K^T   (lane: q = mf*16 + hi*4 + r, key = nf*16 + lo)
    f32x4 sacc[2][4] = {};
#pragma unroll
    for (int kc = 0; kc < 4; ++kc) {
      bf16x8 kf[4];
#pragma unroll
      for (int nf = 0; nf < 4; ++nf) {
        const int key = nf * 16 + lo;
        kf[nf] = *(const bf16x8*)&Klds[key * 128 + ((kc * 32 + hi * 8) ^ ((key & 7) << 3))];
      }
#pragma unroll
      for (int mf = 0; mf < 2; ++mf)
#pragma unroll
        for (int nf = 0; nf < 4; ++nf)
          sacc[mf][nf] = MFMA16(qf[mf][kc], kf[nf], sacc[mf][nf]);
    }

    // ---- online softmax (row reduce across lanes 0..15)
#pragma unroll
    for (int mf = 0; mf < 2; ++mf) {
#pragma unroll
      for (int r = 0; r < 4; ++r) {
        float mx = fmaxf(fmaxf(sacc[mf][0][r], sacc[mf][1][r]),
                         fmaxf(sacc[mf][2][r], sacc[mf][3][r]));
#pragma unroll
        for (int s = 1; s < 16; s <<= 1) mx = fmaxf(mx, __shfl_xor(mx, s, 64));
        const float mold = mrow[mf][r];
        const float mnew = fmaxf(mold, mx);
        const float fs = __expf(mold - mnew);
        mrow[mf][r] = mnew;
        float ps = 0.f;
#pragma unroll
        for (int nf = 0; nf < 4; ++nf) {
          const float p = __expf(sacc[mf][nf][r] - mnew);
          sacc[mf][nf][r] = p;
          ps += p;
        }
#pragma unroll
        for (int s = 1; s < 16; s <<= 1) ps += __shfl_xor(ps, s, 64);
        lrow[mf][r] = lrow[mf][r] * fs + ps;
#pragma unroll
        for (int df = 0; df < 8; ++df) acc_o[mf][df][r] *= fs;
      }
    }

    // ---- P (bf16) -> per-wave LDS, then PV
#pragma unroll
    for (int mf = 0; mf < 2; ++mf)
#pragma unroll
      for (int nf = 0; nf < 4; ++nf)
#pragma unroll
        for (int r = 0; r < 4; ++r)
          Pw[(mf * 16 + hi * 4 + r) * 72 + nf * 16 + lo] = f2bf(sacc[mf][nf][r]);

#pragma unroll
    for (int kc = 0; kc < 2; ++kc) {
      bf16x8 pf[2];
#pragma unroll
      for (int mf = 0; mf < 2; ++mf)
        pf[mf] = *(const bf16x8*)&Pw[(mf * 16 + lo) * 72 + kc * 32 + hi * 8];
#pragma unroll
      for (int df = 0; df < 8; ++df) {
        const int d = df * 16 + lo;
        bf16x8 vf = *(const bf16x8*)&Vt[d * 64 + ((kc * 32 + hi * 8) ^ (((d >> 3) & 7) << 3))];
#pragma unroll
        for (int mf = 0; mf < 2; ++mf)
          acc_o[mf][df] = MFMA16(pf[mf], vf, acc_o[mf][df]);
      }
    }
  }

  // ---- normalize + write bf16 attn to ws [4096][2048]
#pragma unroll
  for (int mf = 0; mf < 2; ++mf) {
    const int qrow = b * 1024 + qb * 256 + w * 32 + mf * 16 + hi * 4;
#pragma unroll
    for (int r = 0; r < 4; ++r) {
      const float inv = 1.f / lrow[mf][r];
      u16* op = attnws + (size_t)(qrow + r) * 2048 + h * 128;
#pragma unroll
      for (int df = 0; df < 8; ++df)
        op[df * 16 + lo] = f2bf(acc_o[mf][df][r] * inv);
    }
  }
}

extern "C" void kernel_launch(void* const* d_in, const int* in_sizes, int n_in,
                              void* d_out, int out_size, void* d_ws, size_t ws_size,
                              hipStream_t stream)
{
  (void)in_sizes; (void)n_in; (void)out_size; (void)ws_size;
  const float* x  = (const float*)d_in[0];
  const float* pk = (const float*)d_in[1];
  const float* pv = (const float*)d_in[2];
  const float* Wq = (const float*)d_in[3];
  const float* bq = (const float*)d_in[4];
  const float* Wk = (const float*)d_in[5];
  const float* bk = (const float*)d_in[6];
  const float* Wv = (const float*)d_in[7];
  const float* bv = (const float*)d_in[8];
  const float* Wo = (const float*)d_in[9];
  const float* bo = (const float*)d_in[10];

  float* out  = (float*)d_out;           // [4096, 2048]
  float* kout = out + 8388608;           // [4,16,4096,128]
  float* vout = kout + 33554432;

  u16* xb  = (u16*)d_ws;                 // x bf16       (8,388,608)
  u16* wqb = xb  + 8388608;              // W bf16 x4    (4,194,304 each)
  u16* wkb = wqb + 4194304;
  u16* wvb = wkb + 4194304;
  u16* wob = wvb + 4194304;
  u16* qb_ = wob + 4194304;              // q bf16 scaled (8,388,608)
  u16* ab  = qb_ + 8388608;              // attn bf16     (8,388,608)

  k_cvt<<<2048, 256, 0, stream>>>(x,  xb,  2097152);
  k_cvt<<<1024, 256, 0, stream>>>(Wq, wqb, 1048576);
  k_cvt<<<1024, 256, 0, stream>>>(Wk, wkb, 1048576);
  k_cvt<<<1024, 256, 0, stream>>>(Wv, wvb, 1048576);
  k_cvt<<<1024, 256, 0, stream>>>(Wo, wob, 1048576);
  k_past<<<2048, 256, 0, stream>>>(pk, kout, 6291456);
  k_past<<<2048, 256, 0, stream>>>(pv, vout, 6291456);

  dim3 gg(32, 16);
  k_gemm<0><<<gg, 256, 0, stream>>>(xb, wqb, bq, nullptr, qb_);
  k_gemm<1><<<gg, 256, 0, stream>>>(xb, wkb, bk, kout, nullptr);
  k_gemm<1><<<gg, 256, 0, stream>>>(xb, wvb, bv, vout, nullptr);
  k_attn<<<256, 512, 0, stream>>>(qb_, kout, vout, ab);
  k_gemm<2><<<gg, 256, 0, stream>>>(ab, wob, bo, out, nullptr);
}